// Round 7
// baseline (498.237 us; speedup 1.0000x reference)
//
#include <hip/hip_runtime.h>
#include <cstdint>
#include <cmath>

typedef unsigned short u16;
typedef unsigned int u32;
typedef __bf16 bf16x8 __attribute__((ext_vector_type(8)));
typedef float f32x4 __attribute__((ext_vector_type(4)));
typedef float f32x16 __attribute__((ext_vector_type(16)));

#define DEV __device__ __forceinline__

DEV u16 f2bf(float f) {
    union { float f; unsigned u; } a; a.f = f;
    unsigned u = a.u;
    return (u16)((u + 0x7FFFu + ((u >> 16) & 1u)) >> 16);   // RNE
}

// pack two positive floats to bf16 pair (round-half-up: +0x8000 then take hi16)
DEV u32 pack2bf(float a, float b) {
    union { float f; u32 u; } ua, ub; ua.f = a; ub.f = b;
    return __builtin_amdgcn_perm(ub.u + 0x8000u, ua.u + 0x8000u, 0x07060302u);
}

DEV float fast_exp2(float x) {          // v_exp_f32 is native exp2
    float r;
    asm("v_exp_f32 %0, %1" : "=v"(r) : "v"(x));
    return r;
}

DEV float fast_rcp(float x) {           // v_rcp_f32, ~1ulp
    float r;
    asm("v_rcp_f32 %0, %1" : "=v"(r) : "v"(x));
    return r;
}

// gelu via A&S 7.1.26 erf (|eps| <= 1.5e-7, branch-free): ~16 VALU ops vs libm erff
DEV float gelu_fast(float v) {
    float z = fabsf(v) * 0.70710678118f;
    float t = fast_rcp(1.f + 0.3275911f * z);
    float poly = ((((1.061405429f * t - 1.453152027f) * t + 1.421413741f) * t
                   - 0.284496736f) * t + 0.254829592f) * t;
    float e = fast_exp2(-z * z * 1.44269504088896f);   // exp(-z^2)
    float erfv = 1.f - poly * e;                        // erf(z), z >= 0
    erfv = copysignf(erfv, v);
    return 0.5f * v * (1.f + erfv);
}

DEV void async16(void* lds, const void* g) {
    __builtin_amdgcn_global_load_lds(
        (const __attribute__((address_space(1))) unsigned int*)g,
        (__attribute__((address_space(3))) unsigned int*)lds, 16, 0, 0);
}

#define LOG2E 1.44269504088896f
#define PHI()   __builtin_amdgcn_s_setprio(1)
#define PLO()   __builtin_amdgcn_s_setprio(0)

// ---------------- fused: weight transposes (blocks 0..12287) + step-embed add (blocks 12288+)
// x+se f32 copy is NOT materialized: out-proj epilogue recomputes it.
__global__ __launch_bounds__(256)
void prep_k(const float* __restrict__ s0, u16* __restrict__ d0,
            const float* __restrict__ s1, u16* __restrict__ d1,
            const float* __restrict__ s2, u16* __restrict__ d2,
            const float* __restrict__ s3, u16* __restrict__ d3,
            const float* __restrict__ x, const float* __restrict__ se,
            const int* __restrict__ ts, u16* __restrict__ xb) {
    int b = blockIdx.x, tid = threadIdx.x;
    if (b < 12288) {
        __shared__ float tile[32][33];
        const float* src; u16* dst; int N, tidx;
        if (b < 3072)      { src = s0; dst = d0; N = 3072; tidx = b; }
        else if (b < 4096) { src = s1; dst = d1; N = 1024; tidx = b - 3072; }
        else if (b < 8192) { src = s2; dst = d2; N = 4096; tidx = b - 4096; }
        else               { src = s3; dst = d3; N = 1024; tidx = b - 8192; }
        int ntx = N >> 5;
        int n0 = (tidx % ntx) * 32, k0 = (tidx / ntx) * 32;
        int K = (b >= 8192) ? 4096 : 1024;
        int tx = tid & 31, ty = tid >> 5;
        #pragma unroll
        for (int i = ty; i < 32; i += 8) tile[i][tx] = src[(size_t)(k0 + i) * N + n0 + tx];
        __syncthreads();
        // write transposed, 4B (2 bf16) per store: tile[a][b] = src[(k0+a)*N + n0+b]
        int jx = tid & 15, iy = tid >> 4;
        #pragma unroll
        for (int i = iy; i < 32; i += 16) {
            ushort2 u2;
            u2.x = f2bf(tile[2 * jx][i]);
            u2.y = f2bf(tile[2 * jx + 1][i]);
            *(ushort2*)&dst[(size_t)(n0 + i) * K + k0 + 2 * jx] = u2;
        }
    } else {
        int st = ts[0]; st = st < 0 ? 0 : (st > 15 ? 15 : st);
        size_t i = (size_t)(b - 12288) * 256 + tid;
        float4 v = ((const float4*)x)[i];
        int c = (int)(i & 255);
        float4 e = ((const float4*)(se + (size_t)st * 1024))[c];
        v.x += e.x; v.y += e.y; v.z += e.z; v.w += e.w;
        ushort4 u; u.x = f2bf(v.x); u.y = f2bf(v.y); u.z = f2bf(v.z); u.w = f2bf(v.w);
        ((ushort4*)xb)[i] = u;
    }
}

// ---------------- bf16 GEMM, 32x32x16 MFMA, BK=64, XOR-swizzled LDS (round-3 proven cfg)
// Block 128x128, 4 waves 2x2, wave-tile 64x64. launch_bounds (256,3): 84 VGPR + 64 AGPR,
// no spill (round-5 lesson: (256,4) forces scratch spill — accumulator alone is 64 AGPR).
// EPI 0: scatter q (scaled 0.125*log2e) / k / v^T.
// EPI 1: res = (x + se[step][col]) + C   (recomputes x_se; addf = x).
// EPI 2: ob0 = bf16(gelu(C)).
// EPI 3: res2 = LN1-recompute(addf=res1, stats, g, b) + C   (y1 never materialized).
template<int EPI>
__global__ __launch_bounds__(256, 3)
void gemm_bt(const u16* __restrict__ A, const u16* __restrict__ Bt,
             const float* __restrict__ bias, int Kdim,
             u16* __restrict__ ob0, u16* __restrict__ ob1, u16* __restrict__ ob2,
             const float* __restrict__ addf, float* __restrict__ outf,
             const float* __restrict__ se_, const int* __restrict__ ts_,
             const float2* __restrict__ lnstats, const float* __restrict__ lng,
             const float* __restrict__ lnb) {
    __shared__ __align__(16) u16 lA[128 * 64];   // 16KB, row 128B = 8 chunks, swz c^(r&7)
    __shared__ __align__(16) u16 lB[128 * 64];
    const int tid = threadIdx.x, wave = tid >> 6, lane = tid & 63;
    const int m5 = lane & 31, h = lane >> 5;
    const int wm = wave >> 1, wn = wave & 1;
    const size_t m0 = (size_t)blockIdx.x * 128, n0 = (size_t)blockIdx.y * 128;
    const size_t kb = (size_t)Kdim * 2;

    f32x16 acc[2][2];
    #pragma unroll
    for (int i = 0; i < 2; i++)
        #pragma unroll
        for (int j = 0; j < 2; j++)
            #pragma unroll
            for (int e = 0; e < 16; e++) acc[i][j][e] = 0.f;

    const char* Ab = (const char*)A + m0 * kb;
    const char* Bb = (const char*)Bt + n0 * kb;

    auto stage = [&](const char* srcbase, u16* ldsb, int k0) {
        #pragma unroll
        for (int j = 0; j < 4; j++) {
            int loff = wave * 4096 + j * 1024 + lane * 16;
            int L = loff >> 4, r = L >> 3, c = L & 7, g = c ^ (r & 7);
            async16((char*)ldsb + loff, srcbase + (size_t)r * kb + (size_t)k0 * 2 + g * 16);
        }
    };

    stage(Ab, lA, 0); stage(Bb, lB, 0);
    const int r7 = m5 & 7;
    for (int k0 = 0; k0 < Kdim; k0 += 64) {
        __syncthreads();
        bf16x8 af[2][4], bfr[2][4];
        #pragma unroll
        for (int ti = 0; ti < 2; ti++) {
            int rowA = wm * 64 + ti * 32 + m5;
            int rowB = wn * 64 + ti * 32 + m5;
            #pragma unroll
            for (int kh = 0; kh < 4; kh++) {
                int cs = (kh * 2 + h) ^ r7;
                af[ti][kh]  = *(const bf16x8*)((const char*)lA + rowA * 128 + cs * 16);
                bfr[ti][kh] = *(const bf16x8*)((const char*)lB + rowB * 128 + cs * 16);
            }
        }
        __syncthreads();
        if (k0 + 64 < Kdim) { stage(Ab, lA, k0 + 64); stage(Bb, lB, k0 + 64); }
        #pragma unroll
        for (int kh = 0; kh < 4; kh++)
            #pragma unroll
            for (int ti = 0; ti < 2; ti++)
                #pragma unroll
                for (int tj = 0; tj < 2; tj++)
                    acc[ti][tj] = __builtin_amdgcn_mfma_f32_32x32x16_bf16(
                        af[ti][kh], bfr[tj][kh], acc[ti][tj], 0, 0, 0);
    }

    // step row for EPI 1 (recompute x+se)
    const float* serow = nullptr;
    if constexpr (EPI == 1) {
        int st = ts_[0]; st = st < 0 ? 0 : (st > 15 ? 15 : st);
        serow = se_ + (size_t)st * 1024;
    }

    // C layout 32x32: col = lane&31, row = (reg&3) + 8*(reg>>2) + 4*(lane>>5)
    #pragma unroll
    for (int ti = 0; ti < 2; ti++) {
        #pragma unroll
        for (int tj = 0; tj < 2; tj++) {
            size_t col = n0 + wn * 64 + tj * 32 + m5;
            float bv = bias[col];
            if constexpr (EPI == 0) {
                size_t t = col >> 10, c = col & 1023, hh = c >> 6, dh = c & 63;
                #pragma unroll
                for (int g = 0; g < 4; g++) {
                    size_t row0 = m0 + wm * 64 + ti * 32 + 4 * h + 8 * g;
                    size_t bq = row0 >> 10, s0 = row0 & 1023;
                    if (t == 0) {
                        #pragma unroll
                        for (int r = 0; r < 4; r++)
                            ob0[((bq * 16 + hh) * 1024 + s0 + r) * 64 + dh] =
                                f2bf((acc[ti][tj][g * 4 + r] + bv) * 0.18033688011112f);
                    } else if (t == 1) {
                        #pragma unroll
                        for (int r = 0; r < 4; r++)
                            ob1[((bq * 16 + hh) * 1024 + s0 + r) * 64 + dh] =
                                f2bf(acc[ti][tj][g * 4 + r] + bv);
                    } else {
                        // V written TRANSPOSED: vt[bh][dh][s]; 4 consecutive s -> 8B store
                        ushort4 tmp;
                        tmp.x = f2bf(acc[ti][tj][g * 4 + 0] + bv);
                        tmp.y = f2bf(acc[ti][tj][g * 4 + 1] + bv);
                        tmp.z = f2bf(acc[ti][tj][g * 4 + 2] + bv);
                        tmp.w = f2bf(acc[ti][tj][g * 4 + 3] + bv);
                        *(ushort4*)(ob2 + ((bq * 16 + hh) * 64 + dh) * 1024 + s0) = tmp;
                    }
                }
            } else if constexpr (EPI == 1) {
                float sev = serow[col];
                #pragma unroll
                for (int g = 0; g < 4; g++)
                    #pragma unroll
                    for (int r = 0; r < 4; r++) {
                        size_t row = m0 + wm * 64 + ti * 32 + 4 * h + 8 * g + r;
                        float val = acc[ti][tj][g * 4 + r] + bv;
                        size_t o = row * 1024 + col;
                        outf[o] = addf[o] + sev + val;   // addf = x; x+se recomputed exactly
                    }
            } else if constexpr (EPI == 2) {
                #pragma unroll
                for (int g = 0; g < 4; g++)
                    #pragma unroll
                    for (int r = 0; r < 4; r++) {
                        size_t row = m0 + wm * 64 + ti * 32 + 4 * h + 8 * g + r;
                        float val = acc[ti][tj][g * 4 + r] + bv;
                        ob0[row * 4096 + col] = f2bf(gelu_fast(val));
                    }
            } else {   // EPI == 3: recompute y1 = LN1(res1) from stats, add C
                float gv_ = lng[col], bv_ = lnb[col];
                #pragma unroll
                for (int g = 0; g < 4; g++)
                    #pragma unroll
                    for (int r = 0; r < 4; r++) {
                        size_t row = m0 + wm * 64 + ti * 32 + 4 * h + 8 * g + r;
                        float val = acc[ti][tj][g * 4 + r] + bv;
                        size_t o = row * 1024 + col;
                        float2 st = lnstats[row];
                        float yv = (addf[o] - st.x) * st.y * gv_ + bv_;
                        outf[o] = yv + val;
                    }
            }
        }
    }
}

// ---------------- flash attention v4: 128-q blocks, kv-split S-phase, (q,dh)-split PV
// S^T via 32x32x16 MFMA, max-free exp2 softmax, P through LDS with h-partner shfl packing.
// 1D grid 1024 with XCD-locality swizzle: XCD x (ids = x mod 8) gets bh in [16x,16x+16)
// -> that XCD's L2 holds exactly its 16 heads' K/V (4MB), each line reused by 8 q-blocks.
__global__ __launch_bounds__(256, 2)
void attn_k(const u16* __restrict__ Q, const u16* __restrict__ K_, const u16* __restrict__ Vt,
            const float* __restrict__ relb, u16* __restrict__ Out) {
    __shared__ __align__(16) u16 sP[128 * 128];   // 32KB [q][kv] rows 256B, swz c16^(q&15); first 16KB = Q stage
    __shared__ __align__(16) u16 sK[128 * 64];    // 16KB [kv][dh] rows 128B, swz c8^(kv&7)
    __shared__ __align__(16) u16 sVt[64 * 128];   // 16KB [dh][kv] rows 256B, swz c16^(dh&15)
    __shared__ float sL[4][128];
    __shared__ float sLinv[128];
    __shared__ float sRel[128];

    const int tid = threadIdx.x, wave = tid >> 6, lane = tid & 63;
    const int m5 = lane & 31, h = lane >> 5;
    const int bid = blockIdx.x;
    const int swz = (bid & 7) * 128 + (bid >> 3);   // bijective (1024 = 8*128)
    const int bh = swz >> 3, q0 = (swz & 7) * 128;
    const size_t base = (size_t)bh * 65536;

    if (tid < 127) sRel[tid] = relb[tid] * LOG2E;   // log2-domain bias

    auto stageK = [&](int kv0) {
        const char* kbp = (const char*)(K_ + base + (size_t)kv0 * 64);
        #pragma unroll
        for (int j = 0; j < 4; j++) {
            int loff = wave * 4096 + j * 1024 + lane * 16;
            int L = loff >> 4, r = L >> 3, c = L & 7, g = c ^ (r & 7);
            async16((char*)sK + loff, kbp + (size_t)r * 128 + g * 16);
        }
    };
    auto stageV = [&](int kv0) {
        const char* vbp = (const char*)(Vt + base) + (size_t)kv0 * 2;
        #pragma unroll
        for (int j = 0; j < 4; j++) {
            int loff = wave * 4096 + j * 1024 + lane * 16;
            int L = loff >> 4, r = L >> 4, c = L & 15, g = c ^ (r & 15);
            async16((char*)sVt + loff, vbp + (size_t)r * 2048 + g * 16);
        }
    };

    {   // stage Q rows q0..q0+127 into sP[0..16KB): [q][dh] rows 128B, swz c8^(q&7)
        const char* qb = (const char*)(Q + base + (size_t)q0 * 64);
        #pragma unroll
        for (int j = 0; j < 4; j++) {
            int loff = wave * 4096 + j * 1024 + lane * 16;
            int L = loff >> 4, r = L >> 3, c = L & 7, g = c ^ (r & 7);
            async16((char*)sP + loff, qb + (size_t)r * 128 + g * 16);
        }
    }
    stageK(0); stageV(0);
    __syncthreads();                               // staging + sRel visible

    // persistent Q B-fragments: qf[qt][s] : n = qt*32+m5, dh-run = 16s + 8h
    bf16x8 qf[4][4];
    #pragma unroll
    for (int qt = 0; qt < 4; qt++) {
        int row = qt * 32 + m5;
        #pragma unroll
        for (int s = 0; s < 4; s++) {
            int cs = (2 * s + h) ^ (m5 & 7);
            qf[qt][s] = *(const bf16x8*)((const char*)sP + row * 128 + cs * 16);
        }
    }
    __syncthreads();                               // Q frags read; sP reusable for P

    const int qh = wave >> 1, dhh = wave & 1;      // PV-phase role
    f32x16 Oacc[2];
    #pragma unroll
    for (int i = 0; i < 2; i++)
        #pragma unroll
        for (int e = 0; e < 16; e++) Oacc[i][e] = 0.f;
    float lsum[4] = {0.f, 0.f, 0.f, 0.f};

    for (int t = 0; t < 8; t++) {
        const int kv0 = t * 128;
        // ---- S-phase: wave handles kv rows [32*wave, +32), all 128 q
        const int kvr = wave * 32 + m5;
        bf16x8 kf[4];
        #pragma unroll
        for (int s = 0; s < 4; s++) {
            int cs = (2 * s + h) ^ (m5 & 7);
            kf[s] = *(const bf16x8*)((const char*)sK + kvr * 128 + cs * 16);
        }
        f32x16 sc[4];
        #pragma unroll
        for (int qt = 0; qt < 4; qt++)
            #pragma unroll
            for (int e = 0; e < 16; e++) sc[qt][e] = 0.f;
        PHI();
        #pragma unroll
        for (int s = 0; s < 4; s++)
            #pragma unroll
            for (int qt = 0; qt < 4; qt++)
                sc[qt] = __builtin_amdgcn_mfma_f32_32x32x16_bf16(kf[s], qf[qt][s], sc[qt], 0, 0, 0);
        PLO();

        // ---- bias + exp2 (log2 domain), lsum accumulate, pack, h-exchange, P store
        const int kvb = kv0 + wave * 32 + 4 * h;   // + 8g + r
        const bool far_lo = (kv0 >= q0 + 190);     // all rel clamp to 0
        const bool far_hi = (kv0 <= q0 - 190);     // all rel clamp to 126
        #pragma unroll
        for (int qt = 0; qt < 4; qt++) {
            const int qs = q0 + qt * 32 + m5;
            if (far_lo || far_hi) {
                float cb = far_lo ? sRel[0] : sRel[126];
                #pragma unroll
                for (int e = 0; e < 16; e++) sc[qt][e] = fast_exp2(sc[qt][e] + cb);
            } else {
                int relbase = qs - kvb + 63;
                #pragma unroll
                for (int g = 0; g < 4; g++)
                    #pragma unroll
                    for (int r = 0; r < 4; r++) {
                        int rel = relbase - 8 * g - r;
                        rel = rel < 0 ? 0 : (rel > 126 ? 126 : rel);
                        sc[qt][4 * g + r] = fast_exp2(sc[qt][4 * g + r] + sRel[rel]);
                    }
            }
            #pragma unroll
            for (int e = 0; e < 16; e++) lsum[qt] += sc[qt][e];
            // pack pairs: pk[g][j] = bf16(sc[4g+2j]),bf16(sc[4g+2j+1])
            u32 pk[4][2];
            #pragma unroll
            for (int g = 0; g < 4; g++) {
                pk[g][0] = pack2bf(sc[qt][4 * g + 0], sc[qt][4 * g + 1]);
                pk[g][1] = pack2bf(sc[qt][4 * g + 2], sc[qt][4 * g + 3]);
            }
            // h-partner exchange: lane h sends pk[2u+1-h], receives partner's pk[2u+h]
            const int q = qt * 32 + m5;
            char* prow = (char*)sP + q * 256;
            #pragma unroll
            for (int u = 0; u < 2; u++) {
                u32 s0 = h ? pk[2 * u][0] : pk[2 * u + 1][0];
                u32 s1 = h ? pk[2 * u][1] : pk[2 * u + 1][1];
                u32 r0 = __shfl_xor((int)s0, 32);
                u32 r1 = __shfl_xor((int)s1, 32);
                uint4 w;
                if (h == 0) { w.x = pk[2 * u][0]; w.y = pk[2 * u][1]; w.z = r0; w.w = r1; }
                else        { w.x = r0; w.y = r1; w.z = pk[2 * u + 1][0]; w.w = pk[2 * u + 1][1]; }
                int c16 = (4 * wave + 2 * u + h) ^ (q & 15);
                *(uint4*)(prow + c16 * 16) = w;
            }
        }
        __syncthreads();                           // P visible; sK consumed; stageV(t) drained
        if (t < 7) stageK(kv0 + 128);              // in flight during PV

        // ---- PV: wave computes O[q 64*qh..+64][dh 32*dhh..+32]
        #pragma unroll
        for (int s = 0; s < 8; s++) {
            int dh = dhh * 32 + m5;
            int cv = (2 * s + h) ^ (dh & 15);
            bf16x8 vf = *(const bf16x8*)((const char*)sVt + dh * 256 + cv * 16);
            #pragma unroll
            for (int qt = 0; qt < 2; qt++) {
                int q = qh * 64 + qt * 32 + m5;
                int cp = (2 * s + h) ^ (q & 15);
                bf16x8 pf = *(const bf16x8*)((const char*)sP + q * 256 + cp * 16);
                PHI();
                Oacc[qt] = __builtin_amdgcn_mfma_f32_32x32x16_bf16(pf, vf, Oacc[qt], 0, 0, 0);
                PLO();
            }
        }
        __syncthreads();                           // PV done: sP/sVt consumed; stageK drained
        if (t < 7) stageV(kv0 + 128);              // in flight during next S-phase
    }

    // ---- lsum reduce: merge h-partners, per-wave write, cross-wave sum
    #pragma unroll
    for (int qt = 0; qt < 4; qt++) lsum[qt] += __shfl_xor(lsum[qt], 32);
    if (h == 0) {
        #pragma unroll
        for (int qt = 0; qt < 4; qt++) sL[wave][qt * 32 + m5] = lsum[qt];
    }
    __syncthreads();
    if (tid < 128) sLinv[tid] = 1.f / (sL[0][tid] + sL[1][tid] + sL[2][tid] + sL[3][tid]);
    __syncthreads();

    // ---- epilogue: C layout col=dh, row = qt*32 + 4h + 8g + r (within wave's 64-q half)
    const int b = bh >> 4, hh = bh & 15;
    const int dh = dhh * 32 + m5;
    #pragma unroll
    for (int qt = 0; qt < 2; qt++) {
        #pragma unroll
        for (int g = 0; g < 4; g++) {
            #pragma unroll
            for (int r = 0; r < 4; r++) {
                int rl = qh * 64 + qt * 32 + 4 * h + 8 * g + r;
                float val = Oacc[qt][4 * g + r] * sLinv[rl];
                size_t s = (size_t)(q0 + rl);
                Out[((size_t)b * 1024 + s) * 1024 + hh * 64 + dh] = f2bf(val);
            }
        }
    }
}

// ---------------- LayerNorm over rows of 1024.
// MODE 0: write f32 output. MODE 1: write bf16 output + per-row (mean,inv) stats only.
template<int MODE>
__global__ __launch_bounds__(256)
void ln_k(const float* __restrict__ in, const float* __restrict__ g, const float* __restrict__ b,
          float* __restrict__ of, u16* __restrict__ ob, float2* __restrict__ stats) {
    __shared__ float ws1[4], ws2[4];
    int row = blockIdx.x, t = threadIdx.x;
    float4 v = ((const float4*)(in + (size_t)row * 1024))[t];
    float s = v.x + v.y + v.z + v.w;
    float s2 = v.x * v.x + v.y * v.y + v.z * v.z + v.w * v.w;
    #pragma unroll
    for (int m = 1; m < 64; m <<= 1) { s += __shfl_xor(s, m); s2 += __shfl_xor(s2, m); }
    if ((t & 63) == 0) { ws1[t >> 6] = s; ws2[t >> 6] = s2; }
    __syncthreads();
    s = ws1[0] + ws1[1] + ws1[2] + ws1[3];
    s2 = ws2[0] + ws2[1] + ws2[2] + ws2[3];
    float mean = s * (1.f / 1024.f);
    float var = s2 * (1.f / 1024.f) - mean * mean;
    float inv = rsqrtf(var + 1e-5f);
    float4 gv = ((const float4*)g)[t], bv = ((const float4*)b)[t];
    float4 o;
    o.x = (v.x - mean) * inv * gv.x + bv.x;
    o.y = (v.y - mean) * inv * gv.y + bv.y;
    o.z = (v.z - mean) * inv * gv.z + bv.z;
    o.w = (v.w - mean) * inv * gv.w + bv.w;
    if constexpr (MODE == 0) {
        ((float4*)(of + (size_t)row * 1024))[t] = o;
    } else {
        ushort4 u; u.x = f2bf(o.x); u.y = f2bf(o.y); u.z = f2bf(o.z); u.w = f2bf(o.w);
        ((ushort4*)(ob + (size_t)row * 1024))[t] = u;
        if (t == 0) stats[row] = make_float2(mean, inv);
    }
}

extern "C" void kernel_launch(void* const* d_in, const int* in_sizes, int n_in,
                              void* d_out, int out_size, void* d_ws, size_t ws_size,
                              hipStream_t stream) {
    (void)in_sizes; (void)n_in; (void)out_size; (void)ws_size;
    const float* x          = (const float*)d_in[0];
    const float* step_embed = (const float*)d_in[1];
    const float* qkv_w      = (const float*)d_in[2];
    const float* qkv_b      = (const float*)d_in[3];
    const float* out_w      = (const float*)d_in[4];
    const float* out_b      = (const float*)d_in[5];
    const float* relb       = (const float*)d_in[6];
    const float* w1         = (const float*)d_in[7];
    const float* b1         = (const float*)d_in[8];
    const float* w2         = (const float*)d_in[9];
    const float* b2         = (const float*)d_in[10];
    const float* ln1g       = (const float*)d_in[11];
    const float* ln1b       = (const float*)d_in[12];
    const float* ln2g       = (const float*)d_in[13];
    const float* ln2b       = (const float*)d_in[14];
    const int*   tstep      = (const int*)d_in[15];
    float* out = (float*)d_out;

    char* p = (char*)d_ws;
    u16* wt_qkv = (u16*)p; p += (size_t)3072 * 1024 * 2;
    u16* wt_out = (u16*)p; p += (size_t)1024 * 1024 * 2;
    u16* wt_w1  = (u16*)p; p += (size_t)4096 * 1024 * 2;
    u16* wt_w2  = (u16*)p; p += (size_t)1024 * 4096 * 2;
    float2* lnstats = (float2*)p; p += (size_t)8192 * 8;     // LN1 per-row (mean, inv)
    u16* xseb   = (u16*)p; p += (size_t)8192 * 1024 * 2;
    u16* qbuf   = (u16*)p; p += (size_t)8192 * 1024 * 2;
    u16* kbuf   = (u16*)p; p += (size_t)8192 * 1024 * 2;
    u16* attnb  = (u16*)p; p += (size_t)8192 * 1024 * 2;
    p += (size_t)8192 * 1024 * 2;                            // PAD: hbuf (64MB from qbuf) must not touch res1
    float* res1 = (float*)p; p += (size_t)8192 * 1024 * 4;
    // aliases (lifetimes disjoint):
    u16*   y1b  = xseb;           // x_se_bf16 dead after QKV GEMM
    u16*   hbuf = qbuf;           // 64MB: spans qbuf+kbuf+attnb+pad; q/k/attn dead after out-proj GEMM
    float* res2 = res1;           // EPI3 reads res1[o] then writes res2[o]: same thread+index, safe
    u16*   vtb  = (u16*)res1;     // V^T (written by QKV epilogue) lives until attn; res1 written after attn

    prep_k<<<dim3(12288 + 8192), dim3(256), 0, stream>>>(qkv_w, wt_qkv, out_w, wt_out,
                                                         w1, wt_w1, w2, wt_w2,
                                                         x, step_embed, tstep, xseb);
    gemm_bt<0><<<dim3(64, 24), dim3(256), 0, stream>>>(xseb, wt_qkv, qkv_b, 1024,
                                                       qbuf, kbuf, vtb, (const float*)nullptr, (float*)nullptr,
                                                       (const float*)nullptr, (const int*)nullptr,
                                                       (const float2*)nullptr, (const float*)nullptr, (const float*)nullptr);
    attn_k<<<dim3(1024), dim3(256), 0, stream>>>(qbuf, kbuf, vtb, relb, attnb);
    gemm_bt<1><<<dim3(64, 8), dim3(256), 0, stream>>>(attnb, wt_out, out_b, 1024,
                                                      (u16*)nullptr, (u16*)nullptr, (u16*)nullptr, x, res1,
                                                      step_embed, tstep,
                                                      (const float2*)nullptr, (const float*)nullptr, (const float*)nullptr);
    ln_k<1><<<dim3(8192), dim3(256), 0, stream>>>(res1, ln1g, ln1b, (float*)nullptr, y1b, lnstats);
    gemm_bt<2><<<dim3(64, 32), dim3(256), 0, stream>>>(y1b, wt_w1, b1, 1024,
                                                       hbuf, (u16*)nullptr, (u16*)nullptr, (const float*)nullptr, (float*)nullptr,
                                                       (const float*)nullptr, (const int*)nullptr,
                                                       (const float2*)nullptr, (const float*)nullptr, (const float*)nullptr);
    gemm_bt<3><<<dim3(64, 8), dim3(256), 0, stream>>>(hbuf, wt_w2, b2, 4096,
                                                      (u16*)nullptr, (u16*)nullptr, (u16*)nullptr, res1, res2,
                                                      (const float*)nullptr, (const int*)nullptr,
                                                      lnstats, ln1g, ln1b);
    ln_k<0><<<dim3(8192), dim3(256), 0, stream>>>(res2, ln2g, ln2b, out, (u16*)nullptr, (float2*)nullptr);
}

// Round 8
// 475.043 us; speedup vs baseline: 1.0488x; 1.0488x over previous
//
#include <hip/hip_runtime.h>
#include <cstdint>
#include <cmath>

typedef unsigned short u16;
typedef unsigned int u32;
typedef __bf16 bf16x8 __attribute__((ext_vector_type(8)));
typedef float f32x4 __attribute__((ext_vector_type(4)));
typedef float f32x16 __attribute__((ext_vector_type(16)));

#define DEV __device__ __forceinline__

DEV u16 f2bf(float f) {
    union { float f; unsigned u; } a; a.f = f;
    unsigned u = a.u;
    return (u16)((u + 0x7FFFu + ((u >> 16) & 1u)) >> 16);   // RNE
}

DEV float bf2f(u16 u) {
    union { u32 u; float f; } a; a.u = (u32)u << 16; return a.f;
}

// pack two positive floats to bf16 pair (round-half-up: +0x8000 then take hi16)
DEV u32 pack2bf(float a, float b) {
    union { float f; u32 u; } ua, ub; ua.f = a; ub.f = b;
    return __builtin_amdgcn_perm(ub.u + 0x8000u, ua.u + 0x8000u, 0x07060302u);
}

DEV float fast_exp2(float x) {          // v_exp_f32 is native exp2
    float r;
    asm("v_exp_f32 %0, %1" : "=v"(r) : "v"(x));
    return r;
}

DEV float fast_rcp(float x) {           // v_rcp_f32, ~1ulp
    float r;
    asm("v_rcp_f32 %0, %1" : "=v"(r) : "v"(x));
    return r;
}

// gelu via A&S 7.1.26 erf (|eps| <= 1.5e-7, branch-free): ~16 VALU ops vs libm erff
DEV float gelu_fast(float v) {
    float z = fabsf(v) * 0.70710678118f;
    float t = fast_rcp(1.f + 0.3275911f * z);
    float poly = ((((1.061405429f * t - 1.453152027f) * t + 1.421413741f) * t
                   - 0.284496736f) * t + 0.254829592f) * t;
    float e = fast_exp2(-z * z * 1.44269504088896f);   // exp(-z^2)
    float erfv = 1.f - poly * e;                        // erf(z), z >= 0
    erfv = copysignf(erfv, v);
    return 0.5f * v * (1.f + erfv);
}

DEV void async16(void* lds, const void* g) {
    __builtin_amdgcn_global_load_lds(
        (const __attribute__((address_space(1))) unsigned int*)g,
        (__attribute__((address_space(3))) unsigned int*)lds, 16, 0, 0);
}

#define LOG2E 1.44269504088896f
#define PHI()   __builtin_amdgcn_s_setprio(1)
#define PLO()   __builtin_amdgcn_s_setprio(0)

// ---------------- fused: weight transposes (blocks 0..12287) + step-embed add (blocks 12288+)
// x+se f32 copy is NOT materialized: out-proj epilogue reads xseb (bf16) for the residual.
__global__ __launch_bounds__(256)
void prep_k(const float* __restrict__ s0, u16* __restrict__ d0,
            const float* __restrict__ s1, u16* __restrict__ d1,
            const float* __restrict__ s2, u16* __restrict__ d2,
            const float* __restrict__ s3, u16* __restrict__ d3,
            const float* __restrict__ x, const float* __restrict__ se,
            const int* __restrict__ ts, u16* __restrict__ xb) {
    int b = blockIdx.x, tid = threadIdx.x;
    if (b < 12288) {
        __shared__ float tile[32][33];
        const float* src; u16* dst; int N, tidx;
        if (b < 3072)      { src = s0; dst = d0; N = 3072; tidx = b; }
        else if (b < 4096) { src = s1; dst = d1; N = 1024; tidx = b - 3072; }
        else if (b < 8192) { src = s2; dst = d2; N = 4096; tidx = b - 4096; }
        else               { src = s3; dst = d3; N = 1024; tidx = b - 8192; }
        int ntx = N >> 5;
        int n0 = (tidx % ntx) * 32, k0 = (tidx / ntx) * 32;
        int K = (b >= 8192) ? 4096 : 1024;
        int tx = tid & 31, ty = tid >> 5;
        #pragma unroll
        for (int i = ty; i < 32; i += 8) tile[i][tx] = src[(size_t)(k0 + i) * N + n0 + tx];
        __syncthreads();
        // write transposed, 4B (2 bf16) per store
        int jx = tid & 15, iy = tid >> 4;
        #pragma unroll
        for (int i = iy; i < 32; i += 16) {
            ushort2 u2;
            u2.x = f2bf(tile[2 * jx][i]);
            u2.y = f2bf(tile[2 * jx + 1][i]);
            *(ushort2*)&dst[(size_t)(n0 + i) * K + k0 + 2 * jx] = u2;
        }
    } else {
        int st = ts[0]; st = st < 0 ? 0 : (st > 15 ? 15 : st);
        size_t i = (size_t)(b - 12288) * 256 + tid;
        float4 v = ((const float4*)x)[i];
        int c = (int)(i & 255);
        float4 e = ((const float4*)(se + (size_t)st * 1024))[c];
        v.x += e.x; v.y += e.y; v.z += e.z; v.w += e.w;
        ushort4 u; u.x = f2bf(v.x); u.y = f2bf(v.y); u.z = f2bf(v.z); u.w = f2bf(v.w);
        ((ushort4*)xb)[i] = u;
    }
}

// ---------------- bf16 GEMM, 32x32x16 MFMA, BK=64, XOR-swizzled LDS (round-3 proven cfg)
// Block 128x128, 4 waves 2x2, wave-tile 64x64. launch_bounds (256,3): 84 VGPR + 64 AGPR,
// no spill (round-5 lesson: (256,4) forces scratch spill — accumulator alone is 64 AGPR).
// EPI 0: scatter q (scaled 0.125*log2e) / k / v^T.
// EPI 1: res1b = bf16( bf2f(addb=xseb) + C )   (residual path in bf16).
// EPI 2: ob0 = bf16(gelu(C)).
// EPI 3: res2(f32) = LN1-recompute(addb=res1b, stats, g, b) + C   (y1 never materialized).
template<int EPI>
__global__ __launch_bounds__(256, 3)
void gemm_bt(const u16* __restrict__ A, const u16* __restrict__ Bt,
             const float* __restrict__ bias, int Kdim,
             u16* __restrict__ ob0, u16* __restrict__ ob1, u16* __restrict__ ob2,
             const u16* __restrict__ addb, float* __restrict__ outf,
             const float2* __restrict__ lnstats, const float* __restrict__ lng,
             const float* __restrict__ lnb) {
    __shared__ __align__(16) u16 lA[128 * 64];   // 16KB, row 128B = 8 chunks, swz c^(r&7)
    __shared__ __align__(16) u16 lB[128 * 64];
    const int tid = threadIdx.x, wave = tid >> 6, lane = tid & 63;
    const int m5 = lane & 31, h = lane >> 5;
    const int wm = wave >> 1, wn = wave & 1;
    const size_t m0 = (size_t)blockIdx.x * 128, n0 = (size_t)blockIdx.y * 128;
    const size_t kb = (size_t)Kdim * 2;

    f32x16 acc[2][2];
    #pragma unroll
    for (int i = 0; i < 2; i++)
        #pragma unroll
        for (int j = 0; j < 2; j++)
            #pragma unroll
            for (int e = 0; e < 16; e++) acc[i][j][e] = 0.f;

    const char* Ab = (const char*)A + m0 * kb;
    const char* Bb = (const char*)Bt + n0 * kb;

    auto stage = [&](const char* srcbase, u16* ldsb, int k0) {
        #pragma unroll
        for (int j = 0; j < 4; j++) {
            int loff = wave * 4096 + j * 1024 + lane * 16;
            int L = loff >> 4, r = L >> 3, c = L & 7, g = c ^ (r & 7);
            async16((char*)ldsb + loff, srcbase + (size_t)r * kb + (size_t)k0 * 2 + g * 16);
        }
    };

    stage(Ab, lA, 0); stage(Bb, lB, 0);
    const int r7 = m5 & 7;
    for (int k0 = 0; k0 < Kdim; k0 += 64) {
        __syncthreads();
        bf16x8 af[2][4], bfr[2][4];
        #pragma unroll
        for (int ti = 0; ti < 2; ti++) {
            int rowA = wm * 64 + ti * 32 + m5;
            int rowB = wn * 64 + ti * 32 + m5;
            #pragma unroll
            for (int kh = 0; kh < 4; kh++) {
                int cs = (kh * 2 + h) ^ r7;
                af[ti][kh]  = *(const bf16x8*)((const char*)lA + rowA * 128 + cs * 16);
                bfr[ti][kh] = *(const bf16x8*)((const char*)lB + rowB * 128 + cs * 16);
            }
        }
        __syncthreads();
        if (k0 + 64 < Kdim) { stage(Ab, lA, k0 + 64); stage(Bb, lB, k0 + 64); }
        #pragma unroll
        for (int kh = 0; kh < 4; kh++)
            #pragma unroll
            for (int ti = 0; ti < 2; ti++)
                #pragma unroll
                for (int tj = 0; tj < 2; tj++)
                    acc[ti][tj] = __builtin_amdgcn_mfma_f32_32x32x16_bf16(
                        af[ti][kh], bfr[tj][kh], acc[ti][tj], 0, 0, 0);
    }

    // C layout 32x32: col = lane&31, row = (reg&3) + 8*(reg>>2) + 4*(lane>>5)
    #pragma unroll
    for (int ti = 0; ti < 2; ti++) {
        #pragma unroll
        for (int tj = 0; tj < 2; tj++) {
            size_t col = n0 + wn * 64 + tj * 32 + m5;
            float bv = bias[col];
            if constexpr (EPI == 0) {
                size_t t = col >> 10, c = col & 1023, hh = c >> 6, dh = c & 63;
                #pragma unroll
                for (int g = 0; g < 4; g++) {
                    size_t row0 = m0 + wm * 64 + ti * 32 + 4 * h + 8 * g;
                    size_t bq = row0 >> 10, s0 = row0 & 1023;
                    if (t == 0) {
                        #pragma unroll
                        for (int r = 0; r < 4; r++)
                            ob0[((bq * 16 + hh) * 1024 + s0 + r) * 64 + dh] =
                                f2bf((acc[ti][tj][g * 4 + r] + bv) * 0.18033688011112f);
                    } else if (t == 1) {
                        #pragma unroll
                        for (int r = 0; r < 4; r++)
                            ob1[((bq * 16 + hh) * 1024 + s0 + r) * 64 + dh] =
                                f2bf(acc[ti][tj][g * 4 + r] + bv);
                    } else {
                        // V written TRANSPOSED: vt[bh][dh][s]; 4 consecutive s -> 8B store
                        ushort4 tmp;
                        tmp.x = f2bf(acc[ti][tj][g * 4 + 0] + bv);
                        tmp.y = f2bf(acc[ti][tj][g * 4 + 1] + bv);
                        tmp.z = f2bf(acc[ti][tj][g * 4 + 2] + bv);
                        tmp.w = f2bf(acc[ti][tj][g * 4 + 3] + bv);
                        *(ushort4*)(ob2 + ((bq * 16 + hh) * 64 + dh) * 1024 + s0) = tmp;
                    }
                }
            } else if constexpr (EPI == 1) {
                #pragma unroll
                for (int g = 0; g < 4; g++)
                    #pragma unroll
                    for (int r = 0; r < 4; r++) {
                        size_t row = m0 + wm * 64 + ti * 32 + 4 * h + 8 * g + r;
                        float val = acc[ti][tj][g * 4 + r] + bv;
                        size_t o = row * 1024 + col;
                        ob0[o] = f2bf(bf2f(addb[o]) + val);   // addb = xseb (x+se in bf16)
                    }
            } else if constexpr (EPI == 2) {
                #pragma unroll
                for (int g = 0; g < 4; g++)
                    #pragma unroll
                    for (int r = 0; r < 4; r++) {
                        size_t row = m0 + wm * 64 + ti * 32 + 4 * h + 8 * g + r;
                        float val = acc[ti][tj][g * 4 + r] + bv;
                        ob0[row * 4096 + col] = f2bf(gelu_fast(val));
                    }
            } else {   // EPI == 3: recompute y1 = LN1(res1b) from stats, add C, write f32
                float gv_ = lng[col], bv_ = lnb[col];
                #pragma unroll
                for (int g = 0; g < 4; g++)
                    #pragma unroll
                    for (int r = 0; r < 4; r++) {
                        size_t row = m0 + wm * 64 + ti * 32 + 4 * h + 8 * g + r;
                        float val = acc[ti][tj][g * 4 + r] + bv;
                        size_t o = row * 1024 + col;
                        float2 st = lnstats[row];
                        float yv = (bf2f(addb[o]) - st.x) * st.y * gv_ + bv_;
                        outf[o] = yv + val;
                    }
            }
        }
    }
}

// ---------------- flash attention v4: 128-q blocks, kv-split S-phase, (q,dh)-split PV
// S^T via 32x32x16 MFMA, max-free exp2 softmax, P through LDS with h-partner shfl packing.
// 1D grid 1024: XCD x gets bh in [16x,16x+16) (same locality as the natural 2D mapping).
__global__ __launch_bounds__(256, 2)
void attn_k(const u16* __restrict__ Q, const u16* __restrict__ K_, const u16* __restrict__ Vt,
            const float* __restrict__ relb, u16* __restrict__ Out) {
    __shared__ __align__(16) u16 sP[128 * 128];   // 32KB [q][kv] rows 256B, swz c16^(q&15); first 16KB = Q stage
    __shared__ __align__(16) u16 sK[128 * 64];    // 16KB [kv][dh] rows 128B, swz c8^(kv&7)
    __shared__ __align__(16) u16 sVt[64 * 128];   // 16KB [dh][kv] rows 256B, swz c16^(dh&15)
    __shared__ float sL[4][128];
    __shared__ float sLinv[128];
    __shared__ float sRel[128];

    const int tid = threadIdx.x, wave = tid >> 6, lane = tid & 63;
    const int m5 = lane & 31, h = lane >> 5;
    const int bid = blockIdx.x;
    const int swz = (bid & 7) * 128 + (bid >> 3);   // bijective (1024 = 8*128)
    const int bh = swz >> 3, q0 = (swz & 7) * 128;
    const size_t base = (size_t)bh * 65536;

    if (tid < 127) sRel[tid] = relb[tid] * LOG2E;   // log2-domain bias

    auto stageK = [&](int kv0) {
        const char* kbp = (const char*)(K_ + base + (size_t)kv0 * 64);
        #pragma unroll
        for (int j = 0; j < 4; j++) {
            int loff = wave * 4096 + j * 1024 + lane * 16;
            int L = loff >> 4, r = L >> 3, c = L & 7, g = c ^ (r & 7);
            async16((char*)sK + loff, kbp + (size_t)r * 128 + g * 16);
        }
    };
    auto stageV = [&](int kv0) {
        const char* vbp = (const char*)(Vt + base) + (size_t)kv0 * 2;
        #pragma unroll
        for (int j = 0; j < 4; j++) {
            int loff = wave * 4096 + j * 1024 + lane * 16;
            int L = loff >> 4, r = L >> 4, c = L & 15, g = c ^ (r & 15);
            async16((char*)sVt + loff, vbp + (size_t)r * 2048 + g * 16);
        }
    };

    {   // stage Q rows q0..q0+127 into sP[0..16KB): [q][dh] rows 128B, swz c8^(q&7)
        const char* qb = (const char*)(Q + base + (size_t)q0 * 64);
        #pragma unroll
        for (int j = 0; j < 4; j++) {
            int loff = wave * 4096 + j * 1024 + lane * 16;
            int L = loff >> 4, r = L >> 3, c = L & 7, g = c ^ (r & 7);
            async16((char*)sP + loff, qb + (size_t)r * 128 + g * 16);
        }
    }
    stageK(0); stageV(0);
    __syncthreads();                               // staging + sRel visible

    // persistent Q B-fragments: qf[qt][s] : n = qt*32+m5, dh-run = 16s + 8h
    bf16x8 qf[4][4];
    #pragma unroll
    for (int qt = 0; qt < 4; qt++) {
        int row = qt * 32 + m5;
        #pragma unroll
        for (int s = 0; s < 4; s++) {
            int cs = (2 * s + h) ^ (m5 & 7);
            qf[qt][s] = *(const bf16x8*)((const char*)sP + row * 128 + cs * 16);
        }
    }
    __syncthreads();                               // Q frags read; sP reusable for P

    const int qh = wave >> 1, dhh = wave & 1;      // PV-phase role
    f32x16 Oacc[2];
    #pragma unroll
    for (int i = 0; i < 2; i++)
        #pragma unroll
        for (int e = 0; e < 16; e++) Oacc[i][e] = 0.f;
    float lsum[4] = {0.f, 0.f, 0.f, 0.f};

    for (int t = 0; t < 8; t++) {
        const int kv0 = t * 128;
        // ---- S-phase: wave handles kv rows [32*wave, +32), all 128 q
        const int kvr = wave * 32 + m5;
        bf16x8 kf[4];
        #pragma unroll
        for (int s = 0; s < 4; s++) {
            int cs = (2 * s + h) ^ (m5 & 7);
            kf[s] = *(const bf16x8*)((const char*)sK + kvr * 128 + cs * 16);
        }
        f32x16 sc[4];
        #pragma unroll
        for (int qt = 0; qt < 4; qt++)
            #pragma unroll
            for (int e = 0; e < 16; e++) sc[qt][e] = 0.f;
        PHI();
        #pragma unroll
        for (int s = 0; s < 4; s++)
            #pragma unroll
            for (int qt = 0; qt < 4; qt++)
                sc[qt] = __builtin_amdgcn_mfma_f32_32x32x16_bf16(kf[s], qf[qt][s], sc[qt], 0, 0, 0);
        PLO();

        // ---- bias + exp2 (log2 domain), lsum accumulate, pack, h-exchange, P store
        const int kvb = kv0 + wave * 32 + 4 * h;   // + 8g + r
        const bool far_lo = (kv0 >= q0 + 190);     // all rel clamp to 0
        const bool far_hi = (kv0 <= q0 - 190);     // all rel clamp to 126
        #pragma unroll
        for (int qt = 0; qt < 4; qt++) {
            const int qs = q0 + qt * 32 + m5;
            if (far_lo || far_hi) {
                float cb = far_lo ? sRel[0] : sRel[126];
                #pragma unroll
                for (int e = 0; e < 16; e++) sc[qt][e] = fast_exp2(sc[qt][e] + cb);
            } else {
                int relbase = qs - kvb + 63;
                #pragma unroll
                for (int g = 0; g < 4; g++)
                    #pragma unroll
                    for (int r = 0; r < 4; r++) {
                        int rel = relbase - 8 * g - r;
                        rel = rel < 0 ? 0 : (rel > 126 ? 126 : rel);
                        sc[qt][4 * g + r] = fast_exp2(sc[qt][4 * g + r] + sRel[rel]);
                    }
            }
            #pragma unroll
            for (int e = 0; e < 16; e++) lsum[qt] += sc[qt][e];
            // pack pairs: pk[g][j] = bf16(sc[4g+2j]),bf16(sc[4g+2j+1])
            u32 pk[4][2];
            #pragma unroll
            for (int g = 0; g < 4; g++) {
                pk[g][0] = pack2bf(sc[qt][4 * g + 0], sc[qt][4 * g + 1]);
                pk[g][1] = pack2bf(sc[qt][4 * g + 2], sc[qt][4 * g + 3]);
            }
            // h-partner exchange: lane h sends pk[2u+1-h], receives partner's pk[2u+h]
            const int q = qt * 32 + m5;
            char* prow = (char*)sP + q * 256;
            #pragma unroll
            for (int u = 0; u < 2; u++) {
                u32 s0 = h ? pk[2 * u][0] : pk[2 * u + 1][0];
                u32 s1 = h ? pk[2 * u][1] : pk[2 * u + 1][1];
                u32 r0 = __shfl_xor((int)s0, 32);
                u32 r1 = __shfl_xor((int)s1, 32);
                uint4 w;
                if (h == 0) { w.x = pk[2 * u][0]; w.y = pk[2 * u][1]; w.z = r0; w.w = r1; }
                else        { w.x = r0; w.y = r1; w.z = pk[2 * u + 1][0]; w.w = pk[2 * u + 1][1]; }
                int c16 = (4 * wave + 2 * u + h) ^ (q & 15);
                *(uint4*)(prow + c16 * 16) = w;
            }
        }
        __syncthreads();                           // P visible; sK consumed; stageV(t) drained
        if (t < 7) stageK(kv0 + 128);              // in flight during PV

        // ---- PV: wave computes O[q 64*qh..+64][dh 32*dhh..+32]
        #pragma unroll
        for (int s = 0; s < 8; s++) {
            int dh = dhh * 32 + m5;
            int cv = (2 * s + h) ^ (dh & 15);
            bf16x8 vf = *(const bf16x8*)((const char*)sVt + dh * 256 + cv * 16);
            #pragma unroll
            for (int qt = 0; qt < 2; qt++) {
                int q = qh * 64 + qt * 32 + m5;
                int cp = (2 * s + h) ^ (q & 15);
                bf16x8 pf = *(const bf16x8*)((const char*)sP + q * 256 + cp * 16);
                PHI();
                Oacc[qt] = __builtin_amdgcn_mfma_f32_32x32x16_bf16(pf, vf, Oacc[qt], 0, 0, 0);
                PLO();
            }
        }
        __syncthreads();                           // PV done: sP/sVt consumed; stageK drained
        if (t < 7) stageV(kv0 + 128);              // in flight during next S-phase
    }

    // ---- lsum reduce: merge h-partners, per-wave write, cross-wave sum
    #pragma unroll
    for (int qt = 0; qt < 4; qt++) lsum[qt] += __shfl_xor(lsum[qt], 32);
    if (h == 0) {
        #pragma unroll
        for (int qt = 0; qt < 4; qt++) sL[wave][qt * 32 + m5] = lsum[qt];
    }
    __syncthreads();
    if (tid < 128) sLinv[tid] = 1.f / (sL[0][tid] + sL[1][tid] + sL[2][tid] + sL[3][tid]);
    __syncthreads();

    // ---- epilogue: C layout col=dh, row = qt*32 + 4h + 8g + r (within wave's 64-q half)
    const int b = bh >> 4, hh = bh & 15;
    const int dh = dhh * 32 + m5;
    #pragma unroll
    for (int qt = 0; qt < 2; qt++) {
        #pragma unroll
        for (int g = 0; g < 4; g++) {
            #pragma unroll
            for (int r = 0; r < 4; r++) {
                int rl = qh * 64 + qt * 32 + 4 * h + 8 * g + r;
                float val = Oacc[qt][4 * g + r] * sLinv[rl];
                size_t s = (size_t)(q0 + rl);
                Out[((size_t)b * 1024 + s) * 1024 + hh * 64 + dh] = f2bf(val);
            }
        }
    }
}

// ---------------- LayerNorm over rows of 1024.
// MODE 0: f32 in -> f32 out. MODE 1: bf16 in -> bf16 out + per-row (mean,inv) stats.
template<int MODE>
__global__ __launch_bounds__(256)
void ln_k(const float* __restrict__ in, const u16* __restrict__ inb,
          const float* __restrict__ g, const float* __restrict__ b,
          float* __restrict__ of, u16* __restrict__ ob, float2* __restrict__ stats) {
    __shared__ float ws1[4], ws2[4];
    int row = blockIdx.x, t = threadIdx.x;
    float4 v;
    if constexpr (MODE == 0) {
        v = ((const float4*)(in + (size_t)row * 1024))[t];
    } else {
        ushort4 uv = ((const ushort4*)(inb + (size_t)row * 1024))[t];
        v.x = bf2f(uv.x); v.y = bf2f(uv.y); v.z = bf2f(uv.z); v.w = bf2f(uv.w);
    }
    float s = v.x + v.y + v.z + v.w;
    float s2 = v.x * v.x + v.y * v.y + v.z * v.z + v.w * v.w;
    #pragma unroll
    for (int m = 1; m < 64; m <<= 1) { s += __shfl_xor(s, m); s2 += __shfl_xor(s2, m); }
    if ((t & 63) == 0) { ws1[t >> 6] = s; ws2[t >> 6] = s2; }
    __syncthreads();
    s = ws1[0] + ws1[1] + ws1[2] + ws1[3];
    s2 = ws2[0] + ws2[1] + ws2[2] + ws2[3];
    float mean = s * (1.f / 1024.f);
    float var = s2 * (1.f / 1024.f) - mean * mean;
    float inv = rsqrtf(var + 1e-5f);
    float4 gv = ((const float4*)g)[t], bv = ((const float4*)b)[t];
    float4 o;
    o.x = (v.x - mean) * inv * gv.x + bv.x;
    o.y = (v.y - mean) * inv * gv.y + bv.y;
    o.z = (v.z - mean) * inv * gv.z + bv.z;
    o.w = (v.w - mean) * inv * gv.w + bv.w;
    if constexpr (MODE == 0) {
        ((float4*)(of + (size_t)row * 1024))[t] = o;
    } else {
        ushort4 u; u.x = f2bf(o.x); u.y = f2bf(o.y); u.z = f2bf(o.z); u.w = f2bf(o.w);
        ((ushort4*)(ob + (size_t)row * 1024))[t] = u;
        if (t == 0) stats[row] = make_float2(mean, inv);
    }
}

extern "C" void kernel_launch(void* const* d_in, const int* in_sizes, int n_in,
                              void* d_out, int out_size, void* d_ws, size_t ws_size,
                              hipStream_t stream) {
    (void)in_sizes; (void)n_in; (void)out_size; (void)ws_size;
    const float* x          = (const float*)d_in[0];
    const float* step_embed = (const float*)d_in[1];
    const float* qkv_w      = (const float*)d_in[2];
    const float* qkv_b      = (const float*)d_in[3];
    const float* out_w      = (const float*)d_in[4];
    const float* out_b      = (const float*)d_in[5];
    const float* relb       = (const float*)d_in[6];
    const float* w1         = (const float*)d_in[7];
    const float* b1         = (const float*)d_in[8];
    const float* w2         = (const float*)d_in[9];
    const float* b2         = (const float*)d_in[10];
    const float* ln1g       = (const float*)d_in[11];
    const float* ln1b       = (const float*)d_in[12];
    const float* ln2g       = (const float*)d_in[13];
    const float* ln2b       = (const float*)d_in[14];
    const int*   tstep      = (const int*)d_in[15];
    float* out = (float*)d_out;

    char* p = (char*)d_ws;
    u16* wt_qkv = (u16*)p; p += (size_t)3072 * 1024 * 2;
    u16* wt_out = (u16*)p; p += (size_t)1024 * 1024 * 2;
    u16* wt_w1  = (u16*)p; p += (size_t)4096 * 1024 * 2;
    u16* wt_w2  = (u16*)p; p += (size_t)1024 * 4096 * 2;
    float2* lnstats = (float2*)p; p += (size_t)8192 * 8;     // LN1 per-row (mean, inv)
    u16* xseb   = (u16*)p; p += (size_t)8192 * 1024 * 2;
    u16* qbuf   = (u16*)p; p += (size_t)8192 * 1024 * 2;
    u16* kbuf   = (u16*)p; p += (size_t)8192 * 1024 * 2;
    u16* attnb  = (u16*)p; p += (size_t)8192 * 1024 * 2;
    p += (size_t)8192 * 1024 * 2;                            // PAD: hbuf (64MB from qbuf) must not touch res1b
    u16* res1b  = (u16*)p; p += (size_t)8192 * 1024 * 2;     // residual-1 in bf16
    float* res2 = (float*)p; p += (size_t)8192 * 1024 * 4;   // residual-2 f32 (separate from res1b!)
    // aliases (lifetimes disjoint):
    u16*   y1b  = xseb;           // xseb dead after out-proj GEMM (its last reader)
    u16*   hbuf = qbuf;           // 64MB: spans qbuf+kbuf+attnb+pad; q/k/attn dead after out-proj GEMM
    u16*   vtb  = res1b;          // V^T (16MB) lives until attn; res1b written by out-proj (after attn)

    prep_k<<<dim3(12288 + 8192), dim3(256), 0, stream>>>(qkv_w, wt_qkv, out_w, wt_out,
                                                         w1, wt_w1, w2, wt_w2,
                                                         x, step_embed, tstep, xseb);
    gemm_bt<0><<<dim3(64, 24), dim3(256), 0, stream>>>(xseb, wt_qkv, qkv_b, 1024,
                                                       qbuf, kbuf, vtb, (const u16*)nullptr, (float*)nullptr,
                                                       (const float2*)nullptr, (const float*)nullptr, (const float*)nullptr);
    attn_k<<<dim3(1024), dim3(256), 0, stream>>>(qbuf, kbuf, vtb, relb, attnb);
    gemm_bt<1><<<dim3(64, 8), dim3(256), 0, stream>>>(attnb, wt_out, out_b, 1024,
                                                      res1b, (u16*)nullptr, (u16*)nullptr, xseb, (float*)nullptr,
                                                      (const float2*)nullptr, (const float*)nullptr, (const float*)nullptr);
    ln_k<1><<<dim3(8192), dim3(256), 0, stream>>>((const float*)nullptr, res1b, ln1g, ln1b,
                                                  (float*)nullptr, y1b, lnstats);
    gemm_bt<2><<<dim3(64, 32), dim3(256), 0, stream>>>(y1b, wt_w1, b1, 1024,
                                                       hbuf, (u16*)nullptr, (u16*)nullptr, (const u16*)nullptr, (float*)nullptr,
                                                       (const float2*)nullptr, (const float*)nullptr, (const float*)nullptr);
    gemm_bt<3><<<dim3(64, 8), dim3(256), 0, stream>>>(hbuf, wt_w2, b2, 4096,
                                                      (u16*)nullptr, (u16*)nullptr, (u16*)nullptr, res1b, res2,
                                                      lnstats, ln1g, ln1b);
    ln_k<0><<<dim3(8192), dim3(256), 0, stream>>>(res2, (const u16*)nullptr, ln2g, ln2b,
                                                  out, (u16*)nullptr, (float2*)nullptr);
}